// Round 1
// baseline (808.918 us; speedup 1.0000x reference)
//
#include <hip/hip_runtime.h>
#include <cmath>

#define S_LEN 1024
#define D_DIM 4096
#define H_NUM 32
#define HD_DIM 128
#define C_LEN 2048
#define T_LEN 3072

using u16 = unsigned short;
typedef __bf16 bf16x8 __attribute__((ext_vector_type(8)));
typedef float f32x4 __attribute__((ext_vector_type(4)));

__device__ __forceinline__ u16 f2bf(float f) {
  unsigned u = __float_as_uint(f);
  return (u16)((u + 0x7FFFu + ((u >> 16) & 1u)) >> 16);  // RNE
}

__device__ __forceinline__ f32x4 mfma16(bf16x8 a, bf16x8 b, f32x4 c) {
  return __builtin_amdgcn_mfma_f32_16x16x32_bf16(a, b, c, 0, 0, 0);
}

// async global->LDS, 16B per lane. LDS dest must be wave-uniform base; HW adds lane*16.
__device__ __forceinline__ void async_cp16(const u16* g, u16* l) {
  __builtin_amdgcn_global_load_lds((const __attribute__((address_space(1))) unsigned int*)g,
                                   (__attribute__((address_space(3))) unsigned int*)l,
                                   16, 0, 0);
}

// ---------------- fp32 -> bf16 convert (weights) ----------------
__global__ __launch_bounds__(256) void cvt_w(const float* __restrict__ src, u16* __restrict__ dst, int n4) {
  int i = blockIdx.x * 256 + threadIdx.x;
  if (i >= n4) return;
  float4 v = ((const float4*)src)[i];
  ushort4 o;
  o.x = f2bf(v.x); o.y = f2bf(v.y); o.z = f2bf(v.z); o.w = f2bf(v.w);
  ((ushort4*)dst)[i] = o;
}

// ---------------- RMSNorm -> bf16 ----------------
__global__ __launch_bounds__(256) void rmsnorm_k(const float* __restrict__ xs, const float* __restrict__ w,
                                                 u16* __restrict__ xn) {
  int row = blockIdx.x, tid = threadIdx.x;
  const float* xr = xs + (size_t)row * D_DIM;
  float4 xv[4];
  float ss = 0.f;
#pragma unroll
  for (int g = 0; g < 4; ++g) {
    xv[g] = *(const float4*)(xr + g * 1024 + tid * 4);
    ss += xv[g].x * xv[g].x + xv[g].y * xv[g].y + xv[g].z * xv[g].z + xv[g].w * xv[g].w;
  }
#pragma unroll
  for (int m = 1; m < 64; m <<= 1) ss += __shfl_xor(ss, m);
  __shared__ float red[4];
  if ((tid & 63) == 0) red[tid >> 6] = ss;
  __syncthreads();
  float rs = rsqrtf((red[0] + red[1] + red[2] + red[3]) * (1.f / D_DIM) + 1e-6f);
  u16* xo = xn + (size_t)row * D_DIM;
#pragma unroll
  for (int g = 0; g < 4; ++g) {
    float4 wv = *(const float4*)(w + g * 1024 + tid * 4);
    ushort4 o;
    o.x = f2bf(xv[g].x * rs * wv.x);
    o.y = f2bf(xv[g].y * rs * wv.y);
    o.z = f2bf(xv[g].z * rs * wv.z);
    o.w = f2bf(xv[g].w * rs * wv.w);
    *(ushort4*)(xo + g * 1024 + tid * 4) = o;
  }
}

// ---------------- GEMM: C[M,N] = A[M,K] * B[N,K]^T ; M=1024, N=K=4096 ----------------
// m97 structure: 128x128 tile, BK=32, 4 waves (2x2), global_load_lds width=16.
__global__ __launch_bounds__(256) void gemm_bt(const u16* __restrict__ A,
                                               const u16* __restrict__ B0, const u16* __restrict__ B1,
                                               const u16* __restrict__ B2,
                                               float* __restrict__ C0, float* __restrict__ C1,
                                               float* __restrict__ C2) {
  __shared__ u16 As[128 * 32];
  __shared__ u16 Bs[128 * 32];
  int tid = threadIdx.x;
  int wave = tid >> 6, lane = tid & 63, quad = lane >> 4, l15 = lane & 15;
  int wm = wave >> 1, wn = wave & 1;
  int m0 = blockIdx.y * 128, n0 = blockIdx.x * 128;
  int bz = blockIdx.z;
  const u16* Bp = (bz == 0) ? B0 : ((bz == 1) ? B1 : B2);
  float* Cp = (bz == 0) ? C0 : ((bz == 1) ? C1 : C2);

  f32x4 acc[4][4];
  const f32x4 zero4 = {0.f, 0.f, 0.f, 0.f};
#pragma unroll
  for (int mt = 0; mt < 4; ++mt)
#pragma unroll
    for (int nt = 0; nt < 4; ++nt) acc[mt][nt] = zero4;

  int ar = tid >> 2, acol = (tid & 3) * 8;
  const u16* ga0 = A + (size_t)(m0 + ar) * D_DIM + acol;
  const u16* ga1 = A + (size_t)(m0 + 64 + ar) * D_DIM + acol;
  const u16* gb0 = Bp + (size_t)(n0 + ar) * D_DIM + acol;
  const u16* gb1 = Bp + (size_t)(n0 + 64 + ar) * D_DIM + acol;
  u16* la0 = As + (wave << 9);        // wave-uniform; HW adds lane*16B
  u16* la1 = As + 2048 + (wave << 9);
  u16* lb0 = Bs + (wave << 9);
  u16* lb1 = Bs + 2048 + (wave << 9);

  for (int k0 = 0; k0 < D_DIM; k0 += 32) {
    __syncthreads();
    async_cp16(ga0 + k0, la0);
    async_cp16(ga1 + k0, la1);
    async_cp16(gb0 + k0, lb0);
    async_cp16(gb1 + k0, lb1);
    asm volatile("s_waitcnt vmcnt(0)" ::: "memory");
    __syncthreads();
    bf16x8 af[4], bfr[4];
#pragma unroll
    for (int mt = 0; mt < 4; ++mt)
      af[mt] = *(const bf16x8*)(As + (wm * 64 + mt * 16 + l15) * 32 + quad * 8);
#pragma unroll
    for (int nt = 0; nt < 4; ++nt)
      bfr[nt] = *(const bf16x8*)(Bs + (wn * 64 + nt * 16 + l15) * 32 + quad * 8);
#pragma unroll
    for (int mt = 0; mt < 4; ++mt)
#pragma unroll
      for (int nt = 0; nt < 4; ++nt) acc[mt][nt] = mfma16(af[mt], bfr[nt], acc[mt][nt]);
  }
#pragma unroll
  for (int mt = 0; mt < 4; ++mt)
#pragma unroll
    for (int nt = 0; nt < 4; ++nt) {
      int col = n0 + wn * 64 + nt * 16 + l15;
#pragma unroll
      for (int r = 0; r < 4; ++r) {
        int rowm = m0 + wm * 64 + mt * 16 + quad * 4 + r;  // C/D: col=lane&15, row=quad*4+reg
        Cp[(size_t)rowm * D_DIM + col] = acc[mt][nt][r];
      }
    }
}

// ---------------- RoPE (offset=C), q gets 1/sqrt(HD) folded in ----------------
__global__ __launch_bounds__(256) void rope_q_k(const float* __restrict__ qlin, u16* __restrict__ qbf) {
  int idx = blockIdx.x * 256 + threadIdx.x;  // S*H*64
  int i = idx & 63, h = (idx >> 6) & 31, s = idx >> 11;
  size_t base = (size_t)s * D_DIM + h * HD_DIM + i;
  float x1 = qlin[base], x2 = qlin[base + 64];
  float invf = expf((float)i * -0.14391156831212790f);  // ln(10000)/64
  float ang = (float)(s + C_LEN) * invf;
  float sn, cs;
  sincosf(ang, &sn, &cs);
  const float sc = 0.08838834764831845f;  // 1/sqrt(128)
  qbf[base] = f2bf((x1 * cs - x2 * sn) * sc);
  qbf[base + 64] = f2bf((x2 * cs + x1 * sn) * sc);
}

__global__ __launch_bounds__(256) void rope_k_k(const float* __restrict__ klin, u16* __restrict__ kc) {
  int idx = blockIdx.x * 256 + threadIdx.x;
  int i = idx & 63, h = (idx >> 6) & 31, s = idx >> 11;
  size_t base = (size_t)s * D_DIM + h * HD_DIM + i;
  float x1 = klin[base], x2 = klin[base + 64];
  float invf = expf((float)i * -0.14391156831212790f);
  float ang = (float)(s + C_LEN) * invf;
  float sn, cs;
  sincosf(ang, &sn, &cs);
  size_t ob = ((size_t)h * T_LEN + C_LEN + s) * HD_DIM + i;
  kc[ob] = f2bf(x1 * cs - x2 * sn);
  kc[ob + 64] = f2bf(x2 * cs + x1 * sn);
}

// ---------------- cache_k (C,H,HD) fp32 -> k_cat (H,T,HD) bf16 ----------------
__global__ __launch_bounds__(256) void cvt_ck(const float* __restrict__ ck, u16* __restrict__ kc) {
  int idx = blockIdx.x * 256 + threadIdx.x;  // C*H*HD/4
  int flat = idx * 4;
  int c = flat >> 12, h = (flat >> 7) & 31, hd = flat & 127;
  float4 v = *(const float4*)(ck + flat);
  ushort4 o;
  o.x = f2bf(v.x); o.y = f2bf(v.y); o.z = f2bf(v.z); o.w = f2bf(v.w);
  *(ushort4*)(kc + ((size_t)h * T_LEN + c) * HD_DIM + hd) = o;
}

// ---------------- V transpose: src [nrows][4096] fp32 -> v_t (H,HD,T) bf16 ----------------
__global__ __launch_bounds__(256) void trans_v(const float* __restrict__ src, u16* __restrict__ vt, int tofs) {
  int h = blockIdx.z, d0 = blockIdx.x * 64, r0 = blockIdx.y * 64;
  __shared__ float tile[64][65];
  int tid = threadIdx.x;
  int rr = tid >> 4, c4 = (tid & 15) * 4;
#pragma unroll
  for (int p = 0; p < 4; ++p) {
    int r = p * 16 + rr;
    float4 v = *(const float4*)(src + (size_t)(r0 + r) * D_DIM + h * HD_DIM + d0 + c4);
    tile[r][c4] = v.x; tile[r][c4 + 1] = v.y; tile[r][c4 + 2] = v.z; tile[r][c4 + 3] = v.w;
  }
  __syncthreads();
#pragma unroll
  for (int p = 0; p < 4; ++p) {
    int dl = p * 16 + rr;
    ushort4 o;
    o.x = f2bf(tile[c4 + 0][dl]);
    o.y = f2bf(tile[c4 + 1][dl]);
    o.z = f2bf(tile[c4 + 2][dl]);
    o.w = f2bf(tile[c4 + 3][dl]);
    *(ushort4*)(vt + ((size_t)h * HD_DIM + d0 + dl) * T_LEN + tofs + r0 + c4) = o;
  }
}

// ---------------- flash attention: grid (qt=16, h=32), 256 thr = 4 waves x 16 q-rows ----------------
__global__ __launch_bounds__(256) void attn_k(const u16* __restrict__ qb, const u16* __restrict__ kc,
                                              const u16* __restrict__ vt, u16* __restrict__ ob) {
  int qt = blockIdx.x, h = blockIdx.y;
  int tid = threadIdx.x, wave = tid >> 6, lane = tid & 63, quad = lane >> 4, l15 = lane & 15;
  __shared__ u16 Ks[64 * 136];   // [key][hd], pad 136 (272B rows, 16B aligned)
  __shared__ u16 Vs[128 * 72];   // [hd][key] transposed, pad 72 (144B rows)
  __shared__ u16 Ps[4 * 16 * 72];  // per-wave P round-trip buffer

  int qrow = qt * 64 + wave * 16 + l15;  // A-frag m = lane&15
  bf16x8 qf[4];
#pragma unroll
  for (int kt = 0; kt < 4; ++kt)
    qf[kt] = *(const bf16x8*)(qb + (size_t)qrow * D_DIM + h * HD_DIM + kt * 32 + quad * 8);

  f32x4 O[8];
  const f32x4 zero4 = {0.f, 0.f, 0.f, 0.f};
#pragma unroll
  for (int i = 0; i < 8; ++i) O[i] = zero4;
  float mrun[4] = {-INFINITY, -INFINITY, -INFINITY, -INFINITY};
  float lrun[4] = {0.f, 0.f, 0.f, 0.f};

  int ktl = tid >> 2, kcc = (tid & 3) * 32;  // K staging: row/col-chunk
  int vd = tid >> 1, vtt = (tid & 1) * 32;   // V staging
  const u16* kg = kc + ((size_t)h * T_LEN + ktl) * HD_DIM + kcc;
  const u16* vg = vt + ((size_t)h * HD_DIM + vd) * T_LEN + vtt;
  u16* kl = Ks + ktl * 136 + kcc;
  u16* vl = Vs + vd * 72 + vtt;

  int nkb = 33 + qt;  // last block (kb==nkb-1) is the diagonal, partially masked
  for (int kb = 0; kb < nkb; ++kb) {
    __syncthreads();
#pragma unroll
    for (int u = 0; u < 4; ++u)
      *(bf16x8*)(kl + u * 8) = *(const bf16x8*)(kg + (size_t)kb * 64 * HD_DIM + u * 8);
#pragma unroll
    for (int u = 0; u < 4; ++u)
      *(bf16x8*)(vl + u * 8) = *(const bf16x8*)(vg + (size_t)kb * 64 + u * 8);
    __syncthreads();

    // S = Q K^T (scaled via q) : 4 n-tiles x 4 k-steps
    f32x4 sc4[4];
#pragma unroll
    for (int nt = 0; nt < 4; ++nt) {
      f32x4 s = zero4;
#pragma unroll
      for (int kt = 0; kt < 4; ++kt) {
        bf16x8 bv = *(const bf16x8*)(Ks + (nt * 16 + l15) * 136 + kt * 32 + quad * 8);
        s = mfma16(qf[kt], bv, s);
      }
      sc4[nt] = s;
    }
    if (kb == nkb - 1) {
#pragma unroll
      for (int nt = 0; nt < 4; ++nt) {
        int t = kb * 64 + nt * 16 + l15;
#pragma unroll
        for (int r = 0; r < 4; ++r) {
          int srow = qt * 64 + wave * 16 + quad * 4 + r;
          if (t > C_LEN + srow) sc4[nt][r] = -INFINITY;
        }
      }
    }
    // online softmax per row (rows quad*4+r; reduce over 16 lanes of the quad group)
    float alpha4[4];
#pragma unroll
    for (int r = 0; r < 4; ++r) {
      float mx = fmaxf(fmaxf(sc4[0][r], sc4[1][r]), fmaxf(sc4[2][r], sc4[3][r]));
      mx = fmaxf(mx, __shfl_xor(mx, 1));
      mx = fmaxf(mx, __shfl_xor(mx, 2));
      mx = fmaxf(mx, __shfl_xor(mx, 4));
      mx = fmaxf(mx, __shfl_xor(mx, 8));
      float nm = fmaxf(mrun[r], mx);
      float al = __expf(mrun[r] - nm);
      float ps = 0.f;
#pragma unroll
      for (int nt = 0; nt < 4; ++nt) {
        float p = __expf(sc4[nt][r] - nm);
        sc4[nt][r] = p;
        ps += p;
      }
      ps += __shfl_xor(ps, 1);
      ps += __shfl_xor(ps, 2);
      ps += __shfl_xor(ps, 4);
      ps += __shfl_xor(ps, 8);
      lrun[r] = lrun[r] * al + ps;
      mrun[r] = nm;
      alpha4[r] = al;
    }
#pragma unroll
    for (int i = 0; i < 8; ++i)
#pragma unroll
      for (int r = 0; r < 4; ++r) O[i][r] *= alpha4[r];

    // P: C-layout -> LDS -> A-layout (m120-verified transform), per-wave region
    u16* pw = Ps + wave * (16 * 72);
#pragma unroll
    for (int nt = 0; nt < 4; ++nt)
#pragma unroll
      for (int r = 0; r < 4; ++r)
        pw[(quad * 4 + r) * 72 + nt * 16 + l15] = f2bf(sc4[nt][r]);
    asm volatile("s_waitcnt lgkmcnt(0)" ::: "memory");

    // O += P V : 2 k-steps x 8 n-tiles (n = hd)
#pragma unroll
    for (int kt2 = 0; kt2 < 2; ++kt2) {
      bf16x8 af = *(const bf16x8*)(pw + l15 * 72 + kt2 * 32 + quad * 8);
#pragma unroll
      for (int nt2 = 0; nt2 < 8; ++nt2) {
        bf16x8 bv = *(const bf16x8*)(Vs + (nt2 * 16 + l15) * 72 + kt2 * 32 + quad * 8);
        O[nt2] = mfma16(af, bv, O[nt2]);
      }
    }
  }
  float inv[4];
#pragma unroll
  for (int r = 0; r < 4; ++r) inv[r] = 1.f / lrun[r];
#pragma unroll
  for (int nt2 = 0; nt2 < 8; ++nt2)
#pragma unroll
    for (int r = 0; r < 4; ++r) {
      int srow = qt * 64 + wave * 16 + quad * 4 + r;
      ob[(size_t)srow * D_DIM + h * HD_DIM + nt2 * 16 + l15] = f2bf(O[nt2][r] * inv[r]);
    }
}

// ---------------- launch ----------------
extern "C" void kernel_launch(void* const* d_in, const int* in_sizes, int n_in,
                              void* d_out, int out_size, void* d_ws, size_t ws_size,
                              hipStream_t stream) {
  const float* xs = (const float*)d_in[0];
  const float* cache_k = (const float*)d_in[1];
  const float* cache_v = (const float*)d_in[2];
  const float* norm_w = (const float*)d_in[3];
  const float* wq = (const float*)d_in[4];
  const float* wk = (const float*)d_in[5];
  const float* wv = (const float*)d_in[6];
  const float* wo = (const float*)d_in[7];
  float* out = (float*)d_out;

  char* ws = (char*)d_ws;
  size_t off = 0;
  auto take = [&](size_t b) -> void* {
    char* p = ws + off;
    off += (b + 255) & ~(size_t)255;
    return (void*)p;
  };
  u16* wq_bf = (u16*)take((size_t)D_DIM * D_DIM * 2);
  u16* wk_bf = (u16*)take((size_t)D_DIM * D_DIM * 2);
  u16* wv_bf = (u16*)take((size_t)D_DIM * D_DIM * 2);
  u16* wo_bf = (u16*)take((size_t)D_DIM * D_DIM * 2);
  u16* xn_bf = (u16*)take((size_t)S_LEN * D_DIM * 2);
  float* q_lin = (float*)take((size_t)S_LEN * D_DIM * 4);
  float* k_lin = (float*)take((size_t)S_LEN * D_DIM * 4);
  float* v_lin = (float*)take((size_t)S_LEN * D_DIM * 4);
  u16* q_bf = (u16*)take((size_t)S_LEN * D_DIM * 2);
  u16* k_cat = (u16*)take((size_t)H_NUM * T_LEN * HD_DIM * 2);
  u16* v_t = (u16*)take((size_t)H_NUM * T_LEN * HD_DIM * 2);
  u16* attn_bf = (u16*)take((size_t)S_LEN * D_DIM * 2);

  int n4w = D_DIM * D_DIM / 4;
  cvt_w<<<n4w / 256, 256, 0, stream>>>(wq, wq_bf, n4w);
  cvt_w<<<n4w / 256, 256, 0, stream>>>(wk, wk_bf, n4w);
  cvt_w<<<n4w / 256, 256, 0, stream>>>(wv, wv_bf, n4w);
  cvt_w<<<n4w / 256, 256, 0, stream>>>(wo, wo_bf, n4w);
  rmsnorm_k<<<S_LEN, 256, 0, stream>>>(xs, norm_w, xn_bf);
  gemm_bt<<<dim3(32, 8, 3), 256, 0, stream>>>(xn_bf, wq_bf, wk_bf, wv_bf, q_lin, k_lin, v_lin);
  rope_q_k<<<(S_LEN * H_NUM * 64) / 256, 256, 0, stream>>>(q_lin, q_bf);
  rope_k_k<<<(S_LEN * H_NUM * 64) / 256, 256, 0, stream>>>(k_lin, k_cat);
  cvt_ck<<<(C_LEN * H_NUM * HD_DIM / 4) / 256, 256, 0, stream>>>(cache_k, k_cat);
  trans_v<<<dim3(2, C_LEN / 64, H_NUM), 256, 0, stream>>>(cache_v, v_t, 0);
  trans_v<<<dim3(2, S_LEN / 64, H_NUM), 256, 0, stream>>>(v_lin, v_t, C_LEN);
  attn_k<<<dim3(16, 32), 256, 0, stream>>>(q_bf, k_cat, v_t, attn_bf);
  gemm_bt<<<dim3(32, 8, 1), 256, 0, stream>>>(attn_bf, wo_bf, wo_bf, wo_bf, out, out, out);
}

// Round 2
// 734.386 us; speedup vs baseline: 1.1015x; 1.1015x over previous
//
#include <hip/hip_runtime.h>
#include <cmath>

#define S_LEN 1024
#define D_DIM 4096
#define H_NUM 32
#define HD_DIM 128
#define C_LEN 2048
#define T_LEN 3072

using u16 = unsigned short;
typedef __bf16 bf16x8 __attribute__((ext_vector_type(8)));
typedef float f32x4 __attribute__((ext_vector_type(4)));

__device__ __forceinline__ u16 f2bf(float f) {
  unsigned u = __float_as_uint(f);
  return (u16)((u + 0x7FFFu + ((u >> 16) & 1u)) >> 16);  // RNE
}

__device__ __forceinline__ f32x4 mfma16(bf16x8 a, bf16x8 b, f32x4 c) {
  return __builtin_amdgcn_mfma_f32_16x16x32_bf16(a, b, c, 0, 0, 0);
}

// async global->LDS, 16B per lane. LDS dest = wave-uniform base + lane*16.
__device__ __forceinline__ void async_cp16(const u16* g, u16* l) {
  __builtin_amdgcn_global_load_lds((const __attribute__((address_space(1))) unsigned int*)g,
                                   (__attribute__((address_space(3))) unsigned int*)l,
                                   16, 0, 0);
}

// ---------------- fp32 -> bf16 convert, all 4 weights in one dispatch ----------------
__global__ __launch_bounds__(256) void cvt_w4(const float* __restrict__ w0, const float* __restrict__ w1,
                                              const float* __restrict__ w2, const float* __restrict__ w3,
                                              u16* __restrict__ dst) {
  int y = blockIdx.y;
  const float* src = (y == 0) ? w0 : (y == 1) ? w1 : (y == 2) ? w2 : w3;
  int i = blockIdx.x * 256 + threadIdx.x;
  float4 v = ((const float4*)src)[i];
  ushort4 o;
  o.x = f2bf(v.x); o.y = f2bf(v.y); o.z = f2bf(v.z); o.w = f2bf(v.w);
  ((ushort4*)(dst + (size_t)y * D_DIM * D_DIM))[i] = o;
}

// ---------------- RMSNorm -> bf16 ----------------
__global__ __launch_bounds__(256) void rmsnorm_k(const float* __restrict__ xs, const float* __restrict__ w,
                                                 u16* __restrict__ xn) {
  int row = blockIdx.x, tid = threadIdx.x;
  const float* xr = xs + (size_t)row * D_DIM;
  float4 xv[4];
  float ss = 0.f;
#pragma unroll
  for (int g = 0; g < 4; ++g) {
    xv[g] = *(const float4*)(xr + g * 1024 + tid * 4);
    ss += xv[g].x * xv[g].x + xv[g].y * xv[g].y + xv[g].z * xv[g].z + xv[g].w * xv[g].w;
  }
#pragma unroll
  for (int m = 1; m < 64; m <<= 1) ss += __shfl_xor(ss, m);
  __shared__ float red[4];
  if ((tid & 63) == 0) red[tid >> 6] = ss;
  __syncthreads();
  float rs = rsqrtf((red[0] + red[1] + red[2] + red[3]) * (1.f / D_DIM) + 1e-6f);
  u16* xo = xn + (size_t)row * D_DIM;
#pragma unroll
  for (int g = 0; g < 4; ++g) {
    float4 wv = *(const float4*)(w + g * 1024 + tid * 4);
    ushort4 o;
    o.x = f2bf(xv[g].x * rs * wv.x);
    o.y = f2bf(xv[g].y * rs * wv.y);
    o.z = f2bf(xv[g].z * rs * wv.z);
    o.w = f2bf(xv[g].w * rs * wv.w);
    *(ushort4*)(xo + g * 1024 + tid * 4) = o;
  }
}

// ---------------- GEMM: C[M,N] = A[M,K] * B[N,K]^T ; BK=64 as two 32-halves ----------------
// 128x128 tile, 4 waves (2x2), global_load_lds width=16, 32 MFMA per barrier pair.
__global__ __launch_bounds__(256) void gemm_bt(const u16* __restrict__ A,
                                               const u16* __restrict__ B0, const u16* __restrict__ B1,
                                               const u16* __restrict__ B2,
                                               float* __restrict__ C0, float* __restrict__ C1,
                                               float* __restrict__ C2) {
  __shared__ u16 As[2 * 128 * 32];  // [half][row][32]
  __shared__ u16 Bs[2 * 128 * 32];
  int tid = threadIdx.x;
  int wave = tid >> 6, lane = tid & 63, quad = lane >> 4, l15 = lane & 15;
  int wm = wave >> 1, wn = wave & 1;
  int m0 = blockIdx.y * 128, n0 = blockIdx.x * 128;
  int bz = blockIdx.z;
  const u16* Bp = (bz == 0) ? B0 : ((bz == 1) ? B1 : B2);
  float* Cp = (bz == 0) ? C0 : ((bz == 1) ? C1 : C2);

  f32x4 acc[4][4];
  const f32x4 zero4 = {0.f, 0.f, 0.f, 0.f};
#pragma unroll
  for (int mt = 0; mt < 4; ++mt)
#pragma unroll
    for (int nt = 0; nt < 4; ++nt) acc[mt][nt] = zero4;

  int ar = tid >> 2, acol = (tid & 3) * 8;
  const u16* ga0 = A + (size_t)(m0 + ar) * D_DIM + acol;
  const u16* ga1 = A + (size_t)(m0 + 64 + ar) * D_DIM + acol;
  const u16* gb0 = Bp + (size_t)(n0 + ar) * D_DIM + acol;
  const u16* gb1 = Bp + (size_t)(n0 + 64 + ar) * D_DIM + acol;

  for (int k0 = 0; k0 < D_DIM; k0 += 64) {
    __syncthreads();
#pragma unroll
    for (int hf = 0; hf < 2; ++hf) {
      async_cp16(ga0 + k0 + hf * 32, As + hf * 4096 + (wave << 9));
      async_cp16(ga1 + k0 + hf * 32, As + hf * 4096 + 2048 + (wave << 9));
      async_cp16(gb0 + k0 + hf * 32, Bs + hf * 4096 + (wave << 9));
      async_cp16(gb1 + k0 + hf * 32, Bs + hf * 4096 + 2048 + (wave << 9));
    }
    asm volatile("s_waitcnt vmcnt(0)" ::: "memory");
    __syncthreads();
#pragma unroll
    for (int hf = 0; hf < 2; ++hf) {
      bf16x8 af[4], bfr[4];
#pragma unroll
      for (int mt = 0; mt < 4; ++mt)
        af[mt] = *(const bf16x8*)(As + hf * 4096 + (wm * 64 + mt * 16 + l15) * 32 + quad * 8);
#pragma unroll
      for (int nt = 0; nt < 4; ++nt)
        bfr[nt] = *(const bf16x8*)(Bs + hf * 4096 + (wn * 64 + nt * 16 + l15) * 32 + quad * 8);
#pragma unroll
      for (int mt = 0; mt < 4; ++mt)
#pragma unroll
        for (int nt = 0; nt < 4; ++nt) acc[mt][nt] = mfma16(af[mt], bfr[nt], acc[mt][nt]);
    }
  }
#pragma unroll
  for (int mt = 0; mt < 4; ++mt)
#pragma unroll
    for (int nt = 0; nt < 4; ++nt) {
      int col = n0 + wn * 64 + nt * 16 + l15;
#pragma unroll
      for (int r = 0; r < 4; ++r) {
        int rowm = m0 + wm * 64 + mt * 16 + quad * 4 + r;  // C/D: col=lane&15, row=quad*4+reg
        Cp[(size_t)rowm * D_DIM + col] = acc[mt][nt][r];
      }
    }
}

// ---------------- RoPE (offset=C): part 0 -> q (scaled), part 1 -> k into k_cat ----------------
__global__ __launch_bounds__(256) void rope_qk(const float* __restrict__ qlin, const float* __restrict__ klin,
                                               u16* __restrict__ qbf, u16* __restrict__ kc) {
  int part = blockIdx.y;
  int idx = blockIdx.x * 256 + threadIdx.x;  // S*H*64
  int i = idx & 63, h = (idx >> 6) & 31, s = idx >> 11;
  size_t base = (size_t)s * D_DIM + h * HD_DIM + i;
  float invf = expf((float)i * -0.14391156831212790f);  // ln(10000)/64
  float ang = (float)(s + C_LEN) * invf;
  float sn, cs;
  sincosf(ang, &sn, &cs);
  if (part == 0) {
    float x1 = qlin[base], x2 = qlin[base + 64];
    const float sc = 0.08838834764831845f;  // 1/sqrt(128)
    qbf[base] = f2bf((x1 * cs - x2 * sn) * sc);
    qbf[base + 64] = f2bf((x2 * cs + x1 * sn) * sc);
  } else {
    float x1 = klin[base], x2 = klin[base + 64];
    size_t ob = ((size_t)h * T_LEN + C_LEN + s) * HD_DIM + i;
    kc[ob] = f2bf(x1 * cs - x2 * sn);
    kc[ob + 64] = f2bf(x2 * cs + x1 * sn);
  }
}

// ---------------- cache_k (C,H,HD) fp32 -> k_cat (H,T,HD) bf16 ----------------
__global__ __launch_bounds__(256) void cvt_ck(const float* __restrict__ ck, u16* __restrict__ kc) {
  int idx = blockIdx.x * 256 + threadIdx.x;
  int flat = idx * 4;
  int c = flat >> 12, h = (flat >> 7) & 31, hd = flat & 127;
  float4 v = *(const float4*)(ck + flat);
  ushort4 o;
  o.x = f2bf(v.x); o.y = f2bf(v.y); o.z = f2bf(v.z); o.w = f2bf(v.w);
  *(ushort4*)(kc + ((size_t)h * T_LEN + c) * HD_DIM + hd) = o;
}

// ---------------- V transpose: cache_v rows [0,2048) + v_lin rows [2048,3072) -> v_t (H,HD,T) ----------------
__global__ __launch_bounds__(256) void trans_v2(const float* __restrict__ cv, const float* __restrict__ vl,
                                                u16* __restrict__ vt) {
  int h = blockIdx.z, d0 = blockIdx.x * 64, r0 = blockIdx.y * 64;
  const float* src;
  int srow;
  if (r0 < C_LEN) { src = cv; srow = r0; } else { src = vl; srow = r0 - C_LEN; }
  __shared__ float tile[64][65];
  int tid = threadIdx.x;
  int rr = tid >> 4, c4 = (tid & 15) * 4;
#pragma unroll
  for (int p = 0; p < 4; ++p) {
    int r = p * 16 + rr;
    float4 v = *(const float4*)(src + (size_t)(srow + r) * D_DIM + h * HD_DIM + d0 + c4);
    tile[r][c4] = v.x; tile[r][c4 + 1] = v.y; tile[r][c4 + 2] = v.z; tile[r][c4 + 3] = v.w;
  }
  __syncthreads();
#pragma unroll
  for (int p = 0; p < 4; ++p) {
    int dl = p * 16 + rr;
    ushort4 o;
    o.x = f2bf(tile[c4 + 0][dl]);
    o.y = f2bf(tile[c4 + 1][dl]);
    o.z = f2bf(tile[c4 + 2][dl]);
    o.w = f2bf(tile[c4 + 3][dl]);
    *(ushort4*)(vt + ((size_t)h * HD_DIM + d0 + dl) * T_LEN + r0 + c4) = o;
  }
}

// ---------------- flash attention, async double-buffered K/V staging ----------------
// grid (qt=16, h=32), 256 thr = 4 waves x 16 q-rows. LDS 64KB -> 2 blocks/CU (= grid/CU).
// K tile [64][128] and V tile [128][64] stored UNPADDED with XOR-swizzled 16B chunks
// (chunk slot = chunk ^ (row & mask)) so global_load_lds's fixed lane->LDS mapping still
// gives 2-way-max bank aliasing on the ds_read_b128 fragment reads.
__global__ __launch_bounds__(256) void attn_k(const u16* __restrict__ qb, const u16* __restrict__ kc,
                                              const u16* __restrict__ vt, u16* __restrict__ ob) {
  __shared__ u16 Kb[2][8192];
  __shared__ u16 Vb[2][8192];
  int qt = blockIdx.x, h = blockIdx.y;
  int tid = threadIdx.x, wave = tid >> 6, lane = tid & 63, quad = lane >> 4, l15 = lane & 15;

  int qrow = qt * 64 + wave * 16 + l15;
  bf16x8 qf[4];
#pragma unroll
  for (int kt = 0; kt < 4; ++kt)
    qf[kt] = *(const bf16x8*)(qb + (size_t)qrow * D_DIM + h * HD_DIM + kt * 32 + quad * 8);

  f32x4 O[8];
  const f32x4 zero4 = {0.f, 0.f, 0.f, 0.f};
#pragma unroll
  for (int i = 0; i < 8; ++i) O[i] = zero4;
  float mrun[4] = {-INFINITY, -INFINITY, -INFINITY, -INFINITY};
  float lrun[4] = {0.f, 0.f, 0.f, 0.f};

  // staging source addressing (swizzled); LDS byte for thread = p*4096 + tid*16
  int kr = tid >> 4;                          // K row (+p*16), 16 chunks/row
  int kcg = (tid & 15) ^ (kr & 15);           // global chunk for this lane's slot
  int vr = tid >> 3;                          // V row (+p*32), 8 chunks/row
  int vcg = (tid & 7) ^ (vr & 7);
  const u16* kg = kc + ((size_t)h * T_LEN + kr) * HD_DIM + kcg * 8;
  const u16* vg = vt + ((size_t)h * HD_DIM + vr) * T_LEN + vcg * 8;

  auto stage = [&](int kb, int buf) {
    const u16* kp = kg + (size_t)kb * 64 * HD_DIM;
    const u16* vp = vg + (size_t)kb * 64;
#pragma unroll
    for (int p = 0; p < 4; ++p) async_cp16(kp + p * 16 * HD_DIM, &Kb[buf][p * 2048 + (wave << 9)]);
#pragma unroll
    for (int p = 0; p < 4; ++p) async_cp16(vp + (size_t)p * 32 * T_LEN, &Vb[buf][p * 2048 + (wave << 9)]);
  };

  stage(0, 0);
  int nkb = 33 + qt;
  for (int kb = 0; kb < nkb; ++kb) {
    int cur = kb & 1;
    asm volatile("s_waitcnt vmcnt(0)" ::: "memory");
    __syncthreads();
    if (kb + 1 < nkb) stage(kb + 1, cur ^ 1);  // flies during this block's compute

    // S = Q K^T
    f32x4 sc4[4];
#pragma unroll
    for (int nt = 0; nt < 4; ++nt) {
      f32x4 s = zero4;
#pragma unroll
      for (int kt = 0; kt < 4; ++kt) {
        int row = nt * 16 + l15;
        bf16x8 bv = *(const bf16x8*)&Kb[cur][row * 128 + (((kt * 4 + quad) ^ l15) * 8)];
        s = mfma16(qf[kt], bv, s);
      }
      sc4[nt] = s;
    }
    if (kb == nkb - 1) {
#pragma unroll
      for (int nt = 0; nt < 4; ++nt) {
        int t = kb * 64 + nt * 16 + l15;
#pragma unroll
        for (int r = 0; r < 4; ++r) {
          int srow = qt * 64 + wave * 16 + quad * 4 + r;
          if (t > C_LEN + srow) sc4[nt][r] = -INFINITY;
        }
      }
    }
    // online softmax (rows quad*4+r; reduce across the 16 lanes of the quad group)
    float alpha4[4];
#pragma unroll
    for (int r = 0; r < 4; ++r) {
      float mx = fmaxf(fmaxf(sc4[0][r], sc4[1][r]), fmaxf(sc4[2][r], sc4[3][r]));
      mx = fmaxf(mx, __shfl_xor(mx, 1));
      mx = fmaxf(mx, __shfl_xor(mx, 2));
      mx = fmaxf(mx, __shfl_xor(mx, 4));
      mx = fmaxf(mx, __shfl_xor(mx, 8));
      float nm = fmaxf(mrun[r], mx);
      float al = __expf(mrun[r] - nm);
      float ps = 0.f;
#pragma unroll
      for (int nt = 0; nt < 4; ++nt) {
        float p = __expf(sc4[nt][r] - nm);
        sc4[nt][r] = p;
        ps += p;
      }
      ps += __shfl_xor(ps, 1);
      ps += __shfl_xor(ps, 2);
      ps += __shfl_xor(ps, 4);
      ps += __shfl_xor(ps, 8);
      lrun[r] = lrun[r] * al + ps;
      mrun[r] = nm;
      alpha4[r] = al;
    }
#pragma unroll
    for (int i = 0; i < 8; ++i)
#pragma unroll
      for (int r = 0; r < 4; ++r) O[i][r] *= alpha4[r];

    // raw barrier: LDS-drain only (keep the prefetch vmcnt in flight!)
    asm volatile("s_waitcnt lgkmcnt(0)\n\ts_barrier" ::: "memory");

    // P round-trip through the just-consumed K half (per-wave region, stride 72)
    u16* pw = &Kb[cur][wave * 1152];
#pragma unroll
    for (int nt = 0; nt < 4; ++nt)
#pragma unroll
      for (int r = 0; r < 4; ++r)
        pw[(quad * 4 + r) * 72 + nt * 16 + l15] = f2bf(sc4[nt][r]);
    asm volatile("s_waitcnt lgkmcnt(0)" ::: "memory");

    // O += P V
#pragma unroll
    for (int kt2 = 0; kt2 < 2; ++kt2) {
      bf16x8 af = *(const bf16x8*)(pw + l15 * 72 + kt2 * 32 + quad * 8);
#pragma unroll
      for (int nt2 = 0; nt2 < 8; ++nt2) {
        int row = nt2 * 16 + l15;
        bf16x8 bv = *(const bf16x8*)&Vb[cur][row * 64 + (((kt2 * 4 + quad) ^ (l15 & 7)) * 8)];
        O[nt2] = mfma16(af, bv, O[nt2]);
      }
    }
  }
  float inv[4];
#pragma unroll
  for (int r = 0; r < 4; ++r) inv[r] = 1.f / lrun[r];
#pragma unroll
  for (int nt2 = 0; nt2 < 8; ++nt2)
#pragma unroll
    for (int r = 0; r < 4; ++r) {
      int srow = qt * 64 + wave * 16 + quad * 4 + r;
      ob[(size_t)srow * D_DIM + h * HD_DIM + nt2 * 16 + l15] = f2bf(O[nt2][r] * inv[r]);
    }
}

// ---------------- launch ----------------
extern "C" void kernel_launch(void* const* d_in, const int* in_sizes, int n_in,
                              void* d_out, int out_size, void* d_ws, size_t ws_size,
                              hipStream_t stream) {
  const float* xs = (const float*)d_in[0];
  const float* cache_k = (const float*)d_in[1];
  const float* cache_v = (const float*)d_in[2];
  const float* norm_w = (const float*)d_in[3];
  const float* wq = (const float*)d_in[4];
  const float* wk = (const float*)d_in[5];
  const float* wv = (const float*)d_in[6];
  const float* wo = (const float*)d_in[7];
  float* out = (float*)d_out;

  char* ws = (char*)d_ws;
  size_t off = 0;
  auto take = [&](size_t b) -> void* {
    char* p = ws + off;
    off += (b + 255) & ~(size_t)255;
    return (void*)p;
  };
  u16* w_bf = (u16*)take((size_t)4 * D_DIM * D_DIM * 2);  // wq,wk,wv,wo contiguous
  u16* wq_bf = w_bf;
  u16* wk_bf = w_bf + (size_t)D_DIM * D_DIM;
  u16* wv_bf = w_bf + (size_t)2 * D_DIM * D_DIM;
  u16* wo_bf = w_bf + (size_t)3 * D_DIM * D_DIM;
  u16* xn_bf = (u16*)take((size_t)S_LEN * D_DIM * 2);
  float* q_lin = (float*)take((size_t)S_LEN * D_DIM * 4);
  float* k_lin = (float*)take((size_t)S_LEN * D_DIM * 4);
  float* v_lin = (float*)take((size_t)S_LEN * D_DIM * 4);
  u16* q_bf = (u16*)take((size_t)S_LEN * D_DIM * 2);
  u16* k_cat = (u16*)take((size_t)H_NUM * T_LEN * HD_DIM * 2);
  u16* v_t = (u16*)take((size_t)H_NUM * T_LEN * HD_DIM * 2);
  u16* attn_bf = (u16*)take((size_t)S_LEN * D_DIM * 2);

  cvt_w4<<<dim3(D_DIM * D_DIM / 4 / 256, 4), 256, 0, stream>>>(wq, wk, wv, wo, w_bf);
  rmsnorm_k<<<S_LEN, 256, 0, stream>>>(xs, norm_w, xn_bf);
  gemm_bt<<<dim3(32, 8, 3), 256, 0, stream>>>(xn_bf, wq_bf, wk_bf, wv_bf, q_lin, k_lin, v_lin);
  rope_qk<<<dim3((S_LEN * H_NUM * 64) / 256, 2), 256, 0, stream>>>(q_lin, k_lin, q_bf, k_cat);
  cvt_ck<<<(C_LEN * H_NUM * HD_DIM / 4) / 256, 256, 0, stream>>>(cache_k, k_cat);
  trans_v2<<<dim3(2, T_LEN / 64, H_NUM), 256, 0, stream>>>(cache_v, v_lin, v_t);
  attn_k<<<dim3(16, 32), 256, 0, stream>>>(q_bf, k_cat, v_t, attn_bf);
  gemm_bt<<<dim3(32, 8, 1), 256, 0, stream>>>(attn_bf, wo_bf, wo_bf, wo_bf, out, out, out);
}

// Round 3
// 716.639 us; speedup vs baseline: 1.1288x; 1.0248x over previous
//
#include <hip/hip_runtime.h>
#include <cmath>

#define S_LEN 1024
#define D_DIM 4096
#define H_NUM 32
#define HD_DIM 128
#define C_LEN 2048
#define T_LEN 3072

using u16 = unsigned short;
typedef __bf16 bf16x8 __attribute__((ext_vector_type(8)));
typedef float f32x4 __attribute__((ext_vector_type(4)));

__device__ __forceinline__ u16 f2bf(float f) {
  unsigned u = __float_as_uint(f);
  return (u16)((u + 0x7FFFu + ((u >> 16) & 1u)) >> 16);  // RNE
}

__device__ __forceinline__ f32x4 mfma16(bf16x8 a, bf16x8 b, f32x4 c) {
  return __builtin_amdgcn_mfma_f32_16x16x32_bf16(a, b, c, 0, 0, 0);
}

// async global->LDS, 16B per lane. LDS dest = wave-uniform base + lane*16.
__device__ __forceinline__ void async_cp16(const u16* g, u16* l) {
  __builtin_amdgcn_global_load_lds((const __attribute__((address_space(1))) unsigned int*)g,
                                   (__attribute__((address_space(3))) unsigned int*)l,
                                   16, 0, 0);
}

// ---------------- fp32 -> bf16 convert, all 4 weights in one dispatch ----------------
__global__ __launch_bounds__(256) void cvt_w4(const float* __restrict__ w0, const float* __restrict__ w1,
                                              const float* __restrict__ w2, const float* __restrict__ w3,
                                              u16* __restrict__ dst) {
  int y = blockIdx.y;
  const float* src = (y == 0) ? w0 : (y == 1) ? w1 : (y == 2) ? w2 : w3;
  int i = blockIdx.x * 256 + threadIdx.x;
  float4 v = ((const float4*)src)[i];
  ushort4 o;
  o.x = f2bf(v.x); o.y = f2bf(v.y); o.z = f2bf(v.z); o.w = f2bf(v.w);
  ((ushort4*)(dst + (size_t)y * D_DIM * D_DIM))[i] = o;
}

// ---------------- RMSNorm -> bf16 ----------------
__global__ __launch_bounds__(256) void rmsnorm_k(const float* __restrict__ xs, const float* __restrict__ w,
                                                 u16* __restrict__ xn) {
  int row = blockIdx.x, tid = threadIdx.x;
  const float* xr = xs + (size_t)row * D_DIM;
  float4 xv[4];
  float ss = 0.f;
#pragma unroll
  for (int g = 0; g < 4; ++g) {
    xv[g] = *(const float4*)(xr + g * 1024 + tid * 4);
    ss += xv[g].x * xv[g].x + xv[g].y * xv[g].y + xv[g].z * xv[g].z + xv[g].w * xv[g].w;
  }
#pragma unroll
  for (int m = 1; m < 64; m <<= 1) ss += __shfl_xor(ss, m);
  __shared__ float red[4];
  if ((tid & 63) == 0) red[tid >> 6] = ss;
  __syncthreads();
  float rs = rsqrtf((red[0] + red[1] + red[2] + red[3]) * (1.f / D_DIM) + 1e-6f);
  u16* xo = xn + (size_t)row * D_DIM;
#pragma unroll
  for (int g = 0; g < 4; ++g) {
    float4 wv = *(const float4*)(w + g * 1024 + tid * 4);
    ushort4 o;
    o.x = f2bf(xv[g].x * rs * wv.x);
    o.y = f2bf(xv[g].y * rs * wv.y);
    o.z = f2bf(xv[g].z * rs * wv.z);
    o.w = f2bf(xv[g].w * rs * wv.w);
    *(ushort4*)(xo + g * 1024 + tid * 4) = o;
  }
}

// ---------------- GEMM: C[M,N] = A[M,K] * B[N,K]^T ----------------
// 128x128 tile, BK=32, 3-stage LDS ring (48KB -> 3 blocks/CU), depth-2 async prefetch,
// raw s_barrier + s_waitcnt vmcnt(8) (never drains to 0 until the tail).
// XOR chunk swizzle: staging lane fetches global chunk (tid&3)^((tid>>3)&3) so that
// chunk c of row r lands at slot c^((r>>1)&3) -> fragment ds_read_b128 is 2-way max.
__global__ __launch_bounds__(256) void gemm_bt(const u16* __restrict__ A,
                                               const u16* __restrict__ B0, const u16* __restrict__ B1,
                                               const u16* __restrict__ B2,
                                               float* __restrict__ C0, float* __restrict__ C1,
                                               float* __restrict__ C2) {
  __shared__ u16 As[3 * 4096];  // 3 stages x [128 rows][32 u16]
  __shared__ u16 Bs[3 * 4096];
  int tid = threadIdx.x;
  int wave = tid >> 6, lane = tid & 63, quad = lane >> 4, l15 = lane & 15;
  int wm = wave >> 1, wn = wave & 1;
  int m0 = blockIdx.y * 128, n0 = blockIdx.x * 128;
  int bz = blockIdx.z;
  const u16* Bp = (bz == 0) ? B0 : ((bz == 1) ? B1 : B2);
  float* Cp = (bz == 0) ? C0 : ((bz == 1) ? C1 : C2);

  f32x4 acc[4][4];
  const f32x4 zero4 = {0.f, 0.f, 0.f, 0.f};
#pragma unroll
  for (int mt = 0; mt < 4; ++mt)
#pragma unroll
    for (int nt = 0; nt < 4; ++nt) acc[mt][nt] = zero4;

  int ar = tid >> 2;                                   // staging row (0..63)
  int acs = ((tid & 3) ^ ((tid >> 3) & 3)) * 8;        // swizzled source chunk (u16 offset)
  const u16* ga0 = A + (size_t)(m0 + ar) * D_DIM + acs;
  const u16* ga1 = A + (size_t)(m0 + 64 + ar) * D_DIM + acs;
  const u16* gb0 = Bp + (size_t)(n0 + ar) * D_DIM + acs;
  const u16* gb1 = Bp + (size_t)(n0 + 64 + ar) * D_DIM + acs;

  auto stage = [&](int k0, int s) {
    async_cp16(ga0 + k0, As + s * 4096 + (wave << 9));
    async_cp16(ga1 + k0, As + s * 4096 + 2048 + (wave << 9));
    async_cp16(gb0 + k0, Bs + s * 4096 + (wave << 9));
    async_cp16(gb1 + k0, Bs + s * 4096 + 2048 + (wave << 9));
  };

  stage(0, 0);
  stage(32, 1);
  int buf = 0;
  int sw = (quad ^ ((l15 >> 1) & 3)) * 8;  // fragment read slot (u16 offset)
  const int NIT = D_DIM / 32;              // 128
  for (int it = 0; it < NIT; ++it) {
    if (it + 2 < NIT) {
      int nb = buf + 2; if (nb >= 3) nb -= 3;
      stage((it + 2) * 32, nb);
      asm volatile("s_waitcnt vmcnt(8)" ::: "memory");   // retire exactly iter it's 4 loads
    } else if (it + 1 < NIT) {
      asm volatile("s_waitcnt vmcnt(4)" ::: "memory");
    } else {
      asm volatile("s_waitcnt vmcnt(0)" ::: "memory");
    }
    asm volatile("s_barrier" ::: "memory");              // all waves' cur loads landed
    const u16* Ab = As + buf * 4096;
    const u16* Bb = Bs + buf * 4096;
    bf16x8 af[4], bfr[4];
#pragma unroll
    for (int mt = 0; mt < 4; ++mt)
      af[mt] = *(const bf16x8*)(Ab + (wm * 64 + mt * 16 + l15) * 32 + sw);
#pragma unroll
    for (int nt = 0; nt < 4; ++nt)
      bfr[nt] = *(const bf16x8*)(Bb + (wn * 64 + nt * 16 + l15) * 32 + sw);
#pragma unroll
    for (int mt = 0; mt < 4; ++mt)
#pragma unroll
      for (int nt = 0; nt < 4; ++nt) acc[mt][nt] = mfma16(af[mt], bfr[nt], acc[mt][nt]);
    asm volatile("s_waitcnt lgkmcnt(0)\n\ts_barrier" ::: "memory");  // ring slot reusable
    if (++buf == 3) buf = 0;
  }
#pragma unroll
  for (int mt = 0; mt < 4; ++mt)
#pragma unroll
    for (int nt = 0; nt < 4; ++nt) {
      int col = n0 + wn * 64 + nt * 16 + l15;
#pragma unroll
      for (int r = 0; r < 4; ++r) {
        int rowm = m0 + wm * 64 + mt * 16 + quad * 4 + r;  // C/D: col=lane&15, row=quad*4+reg
        Cp[(size_t)rowm * D_DIM + col] = acc[mt][nt][r];
      }
    }
}

// ---------------- RoPE (offset=C): part 0 -> q (scaled), part 1 -> k into k_cat ----------------
__global__ __launch_bounds__(256) void rope_qk(const float* __restrict__ qlin, const float* __restrict__ klin,
                                               u16* __restrict__ qbf, u16* __restrict__ kc) {
  int part = blockIdx.y;
  int idx = blockIdx.x * 256 + threadIdx.x;  // S*H*64
  int i = idx & 63, h = (idx >> 6) & 31, s = idx >> 11;
  size_t base = (size_t)s * D_DIM + h * HD_DIM + i;
  float invf = expf((float)i * -0.14391156831212790f);  // ln(10000)/64
  float ang = (float)(s + C_LEN) * invf;
  float sn, cs;
  sincosf(ang, &sn, &cs);
  if (part == 0) {
    float x1 = qlin[base], x2 = qlin[base + 64];
    const float sc = 0.08838834764831845f;  // 1/sqrt(128)
    qbf[base] = f2bf((x1 * cs - x2 * sn) * sc);
    qbf[base + 64] = f2bf((x2 * cs + x1 * sn) * sc);
  } else {
    float x1 = klin[base], x2 = klin[base + 64];
    size_t ob = ((size_t)h * T_LEN + C_LEN + s) * HD_DIM + i;
    kc[ob] = f2bf(x1 * cs - x2 * sn);
    kc[ob + 64] = f2bf(x2 * cs + x1 * sn);
  }
}

// ---------------- cache_k (C,H,HD) fp32 -> k_cat (H,T,HD) bf16 ----------------
__global__ __launch_bounds__(256) void cvt_ck(const float* __restrict__ ck, u16* __restrict__ kc) {
  int idx = blockIdx.x * 256 + threadIdx.x;
  int flat = idx * 4;
  int c = flat >> 12, h = (flat >> 7) & 31, hd = flat & 127;
  float4 v = *(const float4*)(ck + flat);
  ushort4 o;
  o.x = f2bf(v.x); o.y = f2bf(v.y); o.z = f2bf(v.z); o.w = f2bf(v.w);
  *(ushort4*)(kc + ((size_t)h * T_LEN + c) * HD_DIM + hd) = o;
}

// ---------------- V transpose: cache_v rows [0,2048) + v_lin rows [2048,3072) -> v_t (H,HD,T) ----------------
__global__ __launch_bounds__(256) void trans_v2(const float* __restrict__ cv, const float* __restrict__ vl,
                                                u16* __restrict__ vt) {
  int h = blockIdx.z, d0 = blockIdx.x * 64, r0 = blockIdx.y * 64;
  const float* src;
  int srow;
  if (r0 < C_LEN) { src = cv; srow = r0; } else { src = vl; srow = r0 - C_LEN; }
  __shared__ float tile[64][65];
  int tid = threadIdx.x;
  int rr = tid >> 4, c4 = (tid & 15) * 4;
#pragma unroll
  for (int p = 0; p < 4; ++p) {
    int r = p * 16 + rr;
    float4 v = *(const float4*)(src + (size_t)(srow + r) * D_DIM + h * HD_DIM + d0 + c4);
    tile[r][c4] = v.x; tile[r][c4 + 1] = v.y; tile[r][c4 + 2] = v.z; tile[r][c4 + 3] = v.w;
  }
  __syncthreads();
#pragma unroll
  for (int p = 0; p < 4; ++p) {
    int dl = p * 16 + rr;
    ushort4 o;
    o.x = f2bf(tile[c4 + 0][dl]);
    o.y = f2bf(tile[c4 + 1][dl]);
    o.z = f2bf(tile[c4 + 2][dl]);
    o.w = f2bf(tile[c4 + 3][dl]);
    *(ushort4*)(vt + ((size_t)h * HD_DIM + d0 + dl) * T_LEN + r0 + c4) = o;
  }
}

// ---------------- flash attention, async double-buffered K/V staging ----------------
__global__ __launch_bounds__(256) void attn_k(const u16* __restrict__ qb, const u16* __restrict__ kc,
                                              const u16* __restrict__ vt, u16* __restrict__ ob) {
  __shared__ u16 Kb[2][8192];
  __shared__ u16 Vb[2][8192];
  int qt = blockIdx.x, h = blockIdx.y;
  int tid = threadIdx.x, wave = tid >> 6, lane = tid & 63, quad = lane >> 4, l15 = lane & 15;

  int qrow = qt * 64 + wave * 16 + l15;
  bf16x8 qf[4];
#pragma unroll
  for (int kt = 0; kt < 4; ++kt)
    qf[kt] = *(const bf16x8*)(qb + (size_t)qrow * D_DIM + h * HD_DIM + kt * 32 + quad * 8);

  f32x4 O[8];
  const f32x4 zero4 = {0.f, 0.f, 0.f, 0.f};
#pragma unroll
  for (int i = 0; i < 8; ++i) O[i] = zero4;
  float mrun[4] = {-INFINITY, -INFINITY, -INFINITY, -INFINITY};
  float lrun[4] = {0.f, 0.f, 0.f, 0.f};

  int kr = tid >> 4;                          // K row (+p*16), 16 chunks/row
  int kcg = (tid & 15) ^ (kr & 15);           // swizzled global chunk
  int vr = tid >> 3;                          // V row (+p*32), 8 chunks/row
  int vcg = (tid & 7) ^ (vr & 7);
  const u16* kg = kc + ((size_t)h * T_LEN + kr) * HD_DIM + kcg * 8;
  const u16* vg = vt + ((size_t)h * HD_DIM + vr) * T_LEN + vcg * 8;

  auto stage = [&](int kb, int buf) {
    const u16* kp = kg + (size_t)kb * 64 * HD_DIM;
    const u16* vp = vg + (size_t)kb * 64;
#pragma unroll
    for (int p = 0; p < 4; ++p) async_cp16(kp + p * 16 * HD_DIM, &Kb[buf][p * 2048 + (wave << 9)]);
#pragma unroll
    for (int p = 0; p < 4; ++p) async_cp16(vp + (size_t)p * 32 * T_LEN, &Vb[buf][p * 2048 + (wave << 9)]);
  };

  stage(0, 0);
  int nkb = 33 + qt;
  for (int kb = 0; kb < nkb; ++kb) {
    int cur = kb & 1;
    asm volatile("s_waitcnt vmcnt(0)" ::: "memory");
    __syncthreads();
    if (kb + 1 < nkb) stage(kb + 1, cur ^ 1);  // flies during this block's compute

    f32x4 sc4[4];
#pragma unroll
    for (int nt = 0; nt < 4; ++nt) {
      f32x4 s = zero4;
#pragma unroll
      for (int kt = 0; kt < 4; ++kt) {
        int row = nt * 16 + l15;
        bf16x8 bv = *(const bf16x8*)&Kb[cur][row * 128 + (((kt * 4 + quad) ^ l15) * 8)];
        s = mfma16(qf[kt], bv, s);
      }
      sc4[nt] = s;
    }
    if (kb == nkb - 1) {
#pragma unroll
      for (int nt = 0; nt < 4; ++nt) {
        int t = kb * 64 + nt * 16 + l15;
#pragma unroll
        for (int r = 0; r < 4; ++r) {
          int srow = qt * 64 + wave * 16 + quad * 4 + r;
          if (t > C_LEN + srow) sc4[nt][r] = -INFINITY;
        }
      }
    }
    float alpha4[4];
#pragma unroll
    for (int r = 0; r < 4; ++r) {
      float mx = fmaxf(fmaxf(sc4[0][r], sc4[1][r]), fmaxf(sc4[2][r], sc4[3][r]));
      mx = fmaxf(mx, __shfl_xor(mx, 1));
      mx = fmaxf(mx, __shfl_xor(mx, 2));
      mx = fmaxf(mx, __shfl_xor(mx, 4));
      mx = fmaxf(mx, __shfl_xor(mx, 8));
      float nm = fmaxf(mrun[r], mx);
      float al = __expf(mrun[r] - nm);
      float ps = 0.f;
#pragma unroll
      for (int nt = 0; nt < 4; ++nt) {
        float p = __expf(sc4[nt][r] - nm);
        sc4[nt][r] = p;
        ps += p;
      }
      ps += __shfl_xor(ps, 1);
      ps += __shfl_xor(ps, 2);
      ps += __shfl_xor(ps, 4);
      ps += __shfl_xor(ps, 8);
      lrun[r] = lrun[r] * al + ps;
      mrun[r] = nm;
      alpha4[r] = al;
    }
#pragma unroll
    for (int i = 0; i < 8; ++i)
#pragma unroll
      for (int r = 0; r < 4; ++r) O[i][r] *= alpha4[r];

    // raw barrier: LDS-drain only (keep the prefetch vmcnt in flight!)
    asm volatile("s_waitcnt lgkmcnt(0)\n\ts_barrier" ::: "memory");

    // P round-trip through the just-consumed K half (per-wave region, stride 72)
    u16* pw = &Kb[cur][wave * 1152];
#pragma unroll
    for (int nt = 0; nt < 4; ++nt)
#pragma unroll
      for (int r = 0; r < 4; ++r)
        pw[(quad * 4 + r) * 72 + nt * 16 + l15] = f2bf(sc4[nt][r]);
    asm volatile("s_waitcnt lgkmcnt(0)" ::: "memory");

#pragma unroll
    for (int kt2 = 0; kt2 < 2; ++kt2) {
      bf16x8 af = *(const bf16x8*)(pw + l15 * 72 + kt2 * 32 + quad * 8);
#pragma unroll
      for (int nt2 = 0; nt2 < 8; ++nt2) {
        int row = nt2 * 16 + l15;
        bf16x8 bv = *(const bf16x8*)&Vb[cur][row * 64 + (((kt2 * 4 + quad) ^ (l15 & 7)) * 8)];
        O[nt2] = mfma16(af, bv, O[nt2]);
      }
    }
  }
  float inv[4];
#pragma unroll
  for (int r = 0; r < 4; ++r) inv[r] = 1.f / lrun[r];
#pragma unroll
  for (int nt2 = 0; nt2 < 8; ++nt2)
#pragma unroll
    for (int r = 0; r < 4; ++r) {
      int srow = qt * 64 + wave * 16 + quad * 4 + r;
      ob[(size_t)srow * D_DIM + h * HD_DIM + nt2 * 16 + l15] = f2bf(O[nt2][r] * inv[r]);
    }
}

// ---------------- launch ----------------
extern "C" void kernel_launch(void* const* d_in, const int* in_sizes, int n_in,
                              void* d_out, int out_size, void* d_ws, size_t ws_size,
                              hipStream_t stream) {
  const float* xs = (const float*)d_in[0];
  const float* cache_k = (const float*)d_in[1];
  const float* cache_v = (const float*)d_in[2];
  const float* norm_w = (const float*)d_in[3];
  const float* wq = (const float*)d_in[4];
  const float* wk = (const float*)d_in[5];
  const float* wv = (const float*)d_in[6];
  const float* wo = (const float*)d_in[7];
  float* out = (float*)d_out;

  char* ws = (char*)d_ws;
  size_t off = 0;
  auto take = [&](size_t b) -> void* {
    char* p = ws + off;
    off += (b + 255) & ~(size_t)255;
    return (void*)p;
  };
  u16* w_bf = (u16*)take((size_t)4 * D_DIM * D_DIM * 2);  // wq,wk,wv,wo contiguous
  u16* wq_bf = w_bf;
  u16* wk_bf = w_bf + (size_t)D_DIM * D_DIM;
  u16* wv_bf = w_bf + (size_t)2 * D_DIM * D_DIM;
  u16* wo_bf = w_bf + (size_t)3 * D_DIM * D_DIM;
  u16* xn_bf = (u16*)take((size_t)S_LEN * D_DIM * 2);
  float* q_lin = (float*)take((size_t)S_LEN * D_DIM * 4);
  float* k_lin = (float*)take((size_t)S_LEN * D_DIM * 4);
  float* v_lin = (float*)take((size_t)S_LEN * D_DIM * 4);
  u16* q_bf = (u16*)take((size_t)S_LEN * D_DIM * 2);
  u16* k_cat = (u16*)take((size_t)H_NUM * T_LEN * HD_DIM * 2);
  u16* v_t = (u16*)take((size_t)H_NUM * T_LEN * HD_DIM * 2);
  u16* attn_bf = (u16*)take((size_t)S_LEN * D_DIM * 2);

  cvt_w4<<<dim3(D_DIM * D_DIM / 4 / 256, 4), 256, 0, stream>>>(wq, wk, wv, wo, w_bf);
  rmsnorm_k<<<S_LEN, 256, 0, stream>>>(xs, norm_w, xn_bf);
  gemm_bt<<<dim3(32, 8, 3), 256, 0, stream>>>(xn_bf, wq_bf, wk_bf, wv_bf, q_lin, k_lin, v_lin);
  rope_qk<<<dim3((S_LEN * H_NUM * 64) / 256, 2), 256, 0, stream>>>(q_lin, k_lin, q_bf, k_cat);
  cvt_ck<<<(C_LEN * H_NUM * HD_DIM / 4) / 256, 256, 0, stream>>>(cache_k, k_cat);
  trans_v2<<<dim3(2, T_LEN / 64, H_NUM), 256, 0, stream>>>(cache_v, v_lin, v_t);
  attn_k<<<dim3(16, 32), 256, 0, stream>>>(q_bf, k_cat, v_t, attn_bf);
  gemm_bt<<<dim3(32, 8, 1), 256, 0, stream>>>(attn_bf, wo_bf, wo_bf, wo_bf, out, out, out);
}